// Round 1
// baseline (160.728 us; speedup 1.0000x reference)
//
#include <hip/hip_runtime.h>
#include <math.h>

// PHOSA interaction loss, MI355X.
// Shapes fixed by the problem:
constexpr int B_   = 256;
constexpr int NS_  = 10475;
constexpr int NO_  = 65536;
constexpr int P_   = 8;
constexpr int KS_  = 1024;
constexpr int KO_  = 2048;
constexpr int NBLK_S = 4;    // blocks per batch for smpl mean
constexpr int NBLK_O = 16;   // blocks per batch for object mean
constexpr float EPS_ = 1e-9f;
constexpr float ZTH_ = 5.0f;

#define DEV_INLINE __device__ __forceinline__

DEV_INLINE float wredsum(float v) {
#pragma unroll
    for (int o = 32; o; o >>= 1) v += __shfl_down(v, o);
    return v;
}
DEV_INLINE float wredmin(float v) {
#pragma unroll
    for (int o = 32; o; o >>= 1) v = fminf(v, __shfl_down(v, o));
    return v;
}
DEV_INLINE float wredmax(float v) {
#pragma unroll
    for (int o = 32; o; o >>= 1) v = fmaxf(v, __shfl_down(v, o));
    return v;
}

// ---------------------------------------------------------------------------
// Kernel A: per-batch component sums (partial, NBLK blocks per batch).
// out[(b*NBLK + blk)*3 + c] = partial sum of component c.
// ---------------------------------------------------------------------------
template <int N, int NBLK>
__global__ __launch_bounds__(256) void batch_sum_kernel(
        const float* __restrict__ v, float* __restrict__ out) {
    const int b   = blockIdx.x / NBLK;
    const int blk = blockIdx.x % NBLK;
    const int chunk = (N + NBLK - 1) / NBLK;
    const int s = blk * chunk;
    const int e = min(N, s + chunk);
    const float* base = v + (size_t)b * N * 3;
    float sx = 0.f, sy = 0.f, sz = 0.f;
    for (int i = s + (int)threadIdx.x; i < e; i += 256) {
        const float* p = base + (size_t)i * 3;
        sx += p[0];
        sy += p[1];
        sz += p[2];
    }
    __shared__ float red[3][4];
    float r0 = wredsum(sx), r1 = wredsum(sy), r2 = wredsum(sz);
    const int lane = threadIdx.x & 63, wv = threadIdx.x >> 6;
    if (lane == 0) { red[0][wv] = r0; red[1][wv] = r1; red[2][wv] = r2; }
    __syncthreads();
    if (threadIdx.x == 0) {
        float* o = out + ((size_t)b * NBLK + blk) * 3;
        o[0] = red[0][0] + red[0][1] + red[0][2] + red[0][3];
        o[1] = red[1][0] + red[1][1] + red[1][2] + red[1][3];
        o[2] = red[2][0] + red[2][1] + red[2][2] + red[2][3];
    }
}

// ---------------------------------------------------------------------------
// Kernel B: finish batch means, compute loss_inter scalar into li[0].
// One block of 256 threads; thread t owns batch t.
// ---------------------------------------------------------------------------
__global__ __launch_bounds__(256) void means_li_kernel(
        const float* __restrict__ sumS, const float* __restrict__ sumO,
        float* __restrict__ li) {
    const int b = threadIdx.x;
    float d2 = 0.f;
#pragma unroll
    for (int c = 0; c < 3; ++c) {
        float ss = 0.f, so = 0.f;
#pragma unroll
        for (int k = 0; k < NBLK_S; ++k) ss += sumS[((size_t)b * NBLK_S + k) * 3 + c];
#pragma unroll
        for (int k = 0; k < NBLK_O; ++k) so += sumO[((size_t)b * NBLK_O + k) * 3 + c];
        const float ms = ss / (float)NS_;
        const float mo = so / (float)NO_;
        const float d = ms - mo;
        d2 += d * d;
    }
    __shared__ float red[4];
    float r = wredsum(d2);
    if ((threadIdx.x & 63) == 0) red[threadIdx.x >> 6] = r;
    __syncthreads();
    if (threadIdx.x == 0) {
        const float tot = red[0] + red[1] + red[2] + red[3];
        li[0] = tot / (3.0f * (float)B_) / (float)B_;
    }
}

// ---------------------------------------------------------------------------
// Kernel C: per-(batch,part) gather statistics.
// out[(b*P+p)*9 + q], q: 0 umin 1 umax 2 wmin 3 wmax 4 zmin 5 zmax 6 sx 7 sy 8 sz
// ---------------------------------------------------------------------------
template <int N, int K>
__global__ __launch_bounds__(256) void part_stats_kernel(
        const float* __restrict__ v, const int* __restrict__ pidx,
        const float* __restrict__ Ks, float* __restrict__ out) {
    const int b = blockIdx.x / P_;
    const int p = blockIdx.x % P_;
    const float fx = Ks[b * 9 + 0];
    const float cx = Ks[b * 9 + 2];
    const float fy = Ks[b * 9 + 4];
    const float cy = Ks[b * 9 + 5];
    const float* base = v + (size_t)b * N * 3;
    const int* idx = pidx + (size_t)p * K;

    float umin = INFINITY, umax = -INFINITY, wmin = INFINITY, wmax = -INFINITY;
    float zmin = INFINITY, zmax = -INFINITY;
    float sx = 0.f, sy = 0.f, sz = 0.f;

    for (int k = threadIdx.x; k < K; k += 256) {
        const int id = idx[k];
        const float* vp = base + (size_t)id * 3;
        const float x = vp[0], y = vp[1], z = vp[2];
        sx += x; sy += y; sz += z;
        zmin = fminf(zmin, z); zmax = fmaxf(zmax, z);
        float u, w;
        {
#pragma clang fp contract(off)
            const float zd = z + EPS_;
            const float x_ = x / zd;
            const float y_ = (-y) / zd;
            u = fx * x_ + cx;
            w = 1.0f - (fy * y_ + cy);
            u = 2.0f * (u - 0.5f);
            w = 2.0f * (w - 0.5f);
        }
        umin = fminf(umin, u); umax = fmaxf(umax, u);
        wmin = fminf(wmin, w); wmax = fmaxf(wmax, w);
    }

    __shared__ float red[4][9];
    float r[9];
    r[0] = wredmin(umin); r[1] = wredmax(umax);
    r[2] = wredmin(wmin); r[3] = wredmax(wmax);
    r[4] = wredmin(zmin); r[5] = wredmax(zmax);
    r[6] = wredsum(sx);   r[7] = wredsum(sy); r[8] = wredsum(sz);
    const int lane = threadIdx.x & 63, wv = threadIdx.x >> 6;
    if (lane == 0) {
#pragma unroll
        for (int q = 0; q < 9; ++q) red[wv][q] = r[q];
    }
    __syncthreads();
    if (threadIdx.x == 0) {
        float* o = out + ((size_t)b * P_ + p) * 9;
        o[0] = fminf(fminf(red[0][0], red[1][0]), fminf(red[2][0], red[3][0]));
        o[1] = fmaxf(fmaxf(red[0][1], red[1][1]), fmaxf(red[2][1], red[3][1]));
        o[2] = fminf(fminf(red[0][2], red[1][2]), fminf(red[2][2], red[3][2]));
        o[3] = fmaxf(fmaxf(red[0][3], red[1][3]), fmaxf(red[2][3], red[3][3]));
        o[4] = fminf(fminf(red[0][4], red[1][4]), fminf(red[2][4], red[3][4]));
        o[5] = fmaxf(fmaxf(red[0][5], red[1][5]), fmaxf(red[2][5], red[3][5]));
        o[6] = red[0][6] + red[1][6] + red[2][6] + red[3][6];
        o[7] = red[0][7] + red[1][7] + red[2][7] + red[3][7];
        o[8] = red[0][8] + red[1][8] + red[2][8] + red[3][8];
    }
}

// ---------------------------------------------------------------------------
// Kernel D: per-batch pair masking + partial sums. One block (64 thr) per batch.
// partial[b*2] = sum(pair_mse*mask), partial[b*2+1] = count.
// ---------------------------------------------------------------------------
__global__ __launch_bounds__(64) void pair_kernel(
        const float* __restrict__ statsS, const float* __restrict__ statsO,
        float* __restrict__ partial) {
#pragma clang fp contract(off)
    const int b = blockIdx.x;
    __shared__ float sS[P_][9];
    __shared__ float sO[P_][9];
    const int t = threadIdx.x;
    for (int i = t; i < 2 * P_ * 9; i += 64) {
        if (i < P_ * 9) sS[i / 9][i % 9] = statsS[(size_t)b * P_ * 9 + i];
        else {
            const int u = i - P_ * 9;
            sO[u / 9][u % 9] = statsO[(size_t)b * P_ * 9 + u];
        }
    }
    __syncthreads();

    const int ps = t >> 3;
    const int po = t & 7;

    // overlap[b, po]: bbox of smpl part po vs bbox of object part po
    const float* ssp = sS[po];
    const float* sop = sO[po];
    const float pcu = (ssp[0] + ssp[1]) * 0.5f;
    const float phu = (ssp[1] - ssp[0]) * 0.5f * 1.5f;
    const float pcw = (ssp[2] + ssp[3]) * 0.5f;
    const float phw = (ssp[3] - ssp[2]) * 0.5f * 1.5f;
    const float px0 = pcu - phu, px1 = pcu + phu;
    const float py0 = pcw - phw, py1 = pcw + phw;
    const float ocu = (sop[0] + sop[1]) * 0.5f;
    const float ohu = (sop[1] - sop[0]) * 0.5f * 1.5f;
    const float ocw = (sop[2] + sop[3]) * 0.5f;
    const float ohw = (sop[3] - sop[2]) * 0.5f * 1.5f;
    const float ox0 = ocu - ohu, ox1 = ocu + ohu;
    const float oy0 = ocw - ohw, oy1 = ocw + ohw;
    const bool ov = !((ox0 > px1) || (px0 > ox1) || (oy0 > py1) || (py0 > oy1));

    // z window: smpl part ps vs object part po
    const float a  = sS[ps][4];
    const float bm = sS[ps][5];
    const float c  = sO[po][4];
    const float d  = sO[po][5];
    const float gap = fminf(fabsf(c - bm), fabsf(a - d));
    const float zd = ((d >= a) && (bm >= c)) ? 0.f : gap;
    const bool m = ov && (zd < ZTH_);

    // pair mse of part means (K is a power of two -> division exact)
    const float ms0 = sS[ps][6] / (float)KS_;
    const float ms1 = sS[ps][7] / (float)KS_;
    const float ms2 = sS[ps][8] / (float)KS_;
    const float mo0 = sO[po][6] / (float)KO_;
    const float mo1 = sO[po][7] / (float)KO_;
    const float mo2 = sO[po][8] / (float)KO_;
    const float d0 = ms0 - mo0, d1 = ms1 - mo1, d2 = ms2 - mo2;
    const float pm = (d0 * d0 + d1 * d1 + d2 * d2) / 3.0f;

    float psum = m ? pm : 0.f;
    float pcnt = m ? 1.f : 0.f;
    psum = wredsum(psum);
    pcnt = wredsum(pcnt);
    if (t == 0) {
        partial[(size_t)b * 2 + 0] = psum;
        partial[(size_t)b * 2 + 1] = pcnt;
    }
}

// ---------------------------------------------------------------------------
// Kernel E: final reduction + output write.
// ---------------------------------------------------------------------------
__global__ __launch_bounds__(256) void final_kernel(
        const float* __restrict__ partial, const float* __restrict__ li,
        float* __restrict__ out) {
    const int t = threadIdx.x;
    float s = partial[(size_t)t * 2 + 0];
    float c = partial[(size_t)t * 2 + 1];
    __shared__ float rs[4], rc[4];
    float ss = wredsum(s), cc = wredsum(c);
    if ((t & 63) == 0) { rs[t >> 6] = ss; rc[t >> 6] = cc; }
    __syncthreads();
    if (t == 0) {
        const float S = rs[0] + rs[1] + rs[2] + rs[3];
        const float C = rc[0] + rc[1] + rc[2] + rc[3];
        out[0] = li[0];
        out[1] = (C > 0.f) ? (S / C) : 0.f;
    }
}

// ---------------------------------------------------------------------------
extern "C" void kernel_launch(void* const* d_in, const int* in_sizes, int n_in,
                              void* d_out, int out_size, void* d_ws, size_t ws_size,
                              hipStream_t stream) {
    const float* smpl = (const float*)d_in[0];
    const float* obj  = (const float*)d_in[1];
    const float* Ks   = (const float*)d_in[2];
    const int*   sidx = (const int*)d_in[3];
    const int*   oidx = (const int*)d_in[4];
    float* out = (float*)d_out;

    float* w = (float*)d_ws;
    float* sumS    = w;                                // B*NBLK_S*3 = 3072
    float* sumO    = sumS + (size_t)B_ * NBLK_S * 3;   // B*NBLK_O*3 = 12288
    float* liw     = sumO + (size_t)B_ * NBLK_O * 3;   // 8 (padded)
    float* statsS  = liw + 8;                          // B*P*9 = 18432
    float* statsO  = statsS + (size_t)B_ * P_ * 9;     // B*P*9 = 18432
    float* partial = statsO + (size_t)B_ * P_ * 9;     // B*2 = 512

    batch_sum_kernel<NS_, NBLK_S><<<B_ * NBLK_S, 256, 0, stream>>>(smpl, sumS);
    batch_sum_kernel<NO_, NBLK_O><<<B_ * NBLK_O, 256, 0, stream>>>(obj, sumO);
    means_li_kernel<<<1, 256, 0, stream>>>(sumS, sumO, liw);
    part_stats_kernel<NS_, KS_><<<B_ * P_, 256, 0, stream>>>(smpl, sidx, Ks, statsS);
    part_stats_kernel<NO_, KO_><<<B_ * P_, 256, 0, stream>>>(obj, oidx, Ks, statsO);
    pair_kernel<<<B_, 64, 0, stream>>>(statsS, statsO, partial);
    final_kernel<<<1, 256, 0, stream>>>(partial, liw, out);
}

// Round 2
// 128.964 us; speedup vs baseline: 1.2463x; 1.2463x over previous
//
#include <hip/hip_runtime.h>
#include <math.h>

// PHOSA interaction loss, MI355X.
// Shapes fixed by the problem:
constexpr int B_   = 256;
constexpr int NS_  = 10475;
constexpr int NO_  = 65536;
constexpr int P_   = 8;
constexpr int KS_  = 1024;
constexpr int KO_  = 2048;
constexpr int NBLK_S = 4;    // blocks per batch for smpl mean
constexpr int NBLK_O = 16;   // blocks per batch for object mean
constexpr float EPS_ = 1e-9f;
constexpr float ZTH_ = 5.0f;

#define DEV_INLINE __device__ __forceinline__

DEV_INLINE float wredsum(float v) {
#pragma unroll
    for (int o = 32; o; o >>= 1) v += __shfl_down(v, o);
    return v;
}
DEV_INLINE float wredmin(float v) {
#pragma unroll
    for (int o = 32; o; o >>= 1) v = fminf(v, __shfl_down(v, o));
    return v;
}
DEV_INLINE float wredmax(float v) {
#pragma unroll
    for (int o = 32; o; o >>= 1) v = fmaxf(v, __shfl_down(v, o));
    return v;
}

// ---------------------------------------------------------------------------
// Kernel A: per-batch component sums (partial, NBLK blocks per batch).
// out[(b*NBLK + blk)*3 + c] = partial sum of component c.
// ---------------------------------------------------------------------------
template <int N, int NBLK>
__global__ __launch_bounds__(256) void batch_sum_kernel(
        const float* __restrict__ v, float* __restrict__ out) {
    const int b   = blockIdx.x / NBLK;
    const int blk = blockIdx.x % NBLK;
    const int chunk = (N + NBLK - 1) / NBLK;
    const int s = blk * chunk;
    const int e = min(N, s + chunk);
    const float* base = v + (size_t)b * N * 3;
    float sx = 0.f, sy = 0.f, sz = 0.f;
    for (int i = s + (int)threadIdx.x; i < e; i += 256) {
        const float* p = base + (size_t)i * 3;
        sx += p[0];
        sy += p[1];
        sz += p[2];
    }
    __shared__ float red[3][4];
    float r0 = wredsum(sx), r1 = wredsum(sy), r2 = wredsum(sz);
    const int lane = threadIdx.x & 63, wv = threadIdx.x >> 6;
    if (lane == 0) { red[0][wv] = r0; red[1][wv] = r1; red[2][wv] = r2; }
    __syncthreads();
    if (threadIdx.x == 0) {
        float* o = out + ((size_t)b * NBLK + blk) * 3;
        o[0] = red[0][0] + red[0][1] + red[0][2] + red[0][3];
        o[1] = red[1][0] + red[1][1] + red[1][2] + red[1][3];
        o[2] = red[2][0] + red[2][1] + red[2][2] + red[2][3];
    }
}

// ---------------------------------------------------------------------------
// Kernel B: finish batch means, compute loss_inter scalar into li[0].
// One block of 256 threads; thread t owns batch t.
// ---------------------------------------------------------------------------
__global__ __launch_bounds__(256) void means_li_kernel(
        const float* __restrict__ sumS, const float* __restrict__ sumO,
        float* __restrict__ li) {
    const int b = threadIdx.x;
    float d2 = 0.f;
#pragma unroll
    for (int c = 0; c < 3; ++c) {
        float ss = 0.f, so = 0.f;
#pragma unroll
        for (int k = 0; k < NBLK_S; ++k) ss += sumS[((size_t)b * NBLK_S + k) * 3 + c];
#pragma unroll
        for (int k = 0; k < NBLK_O; ++k) so += sumO[((size_t)b * NBLK_O + k) * 3 + c];
        const float ms = ss / (float)NS_;
        const float mo = so / (float)NO_;
        const float d = ms - mo;
        d2 += d * d;
    }
    __shared__ float red[4];
    float r = wredsum(d2);
    if ((threadIdx.x & 63) == 0) red[threadIdx.x >> 6] = r;
    __syncthreads();
    if (threadIdx.x == 0) {
        const float tot = red[0] + red[1] + red[2] + red[3];
        li[0] = tot / (3.0f * (float)B_) / (float)B_;
    }
}

// ---------------------------------------------------------------------------
// Kernel C: per-(batch,part) gather statistics.
// XCD-aware mapping: b = blockIdx % B, p = blockIdx / B, so the P_ blocks that
// gather from the same per-batch vertex window share blockIdx mod 8 -> land on
// the same XCD -> the window is fetched into ONE L2, not eight.
// out[(b*P+p)*9 + q], q: 0 umin 1 umax 2 wmin 3 wmax 4 zmin 5 zmax 6 sx 7 sy 8 sz
// ---------------------------------------------------------------------------
template <int N, int K>
__global__ __launch_bounds__(256) void part_stats_kernel(
        const float* __restrict__ v, const int* __restrict__ pidx,
        const float* __restrict__ Ks, float* __restrict__ out) {
    const int b = blockIdx.x % B_;
    const int p = blockIdx.x / B_;
    const float fx = Ks[b * 9 + 0];
    const float cx = Ks[b * 9 + 2];
    const float fy = Ks[b * 9 + 4];
    const float cy = Ks[b * 9 + 5];
    const float* base = v + (size_t)b * N * 3;
    const int* idx = pidx + (size_t)p * K;

    float umin = INFINITY, umax = -INFINITY, wmin = INFINITY, wmax = -INFINITY;
    float zmin = INFINITY, zmax = -INFINITY;
    float sx = 0.f, sy = 0.f, sz = 0.f;

    constexpr int ITER = K / 256;
    int ids[ITER];
#pragma unroll
    for (int j = 0; j < ITER; ++j) ids[j] = idx[threadIdx.x + j * 256];

#pragma unroll
    for (int j = 0; j < ITER; ++j) {
        const float* vp = base + (size_t)ids[j] * 3;
        const float x = vp[0], y = vp[1], z = vp[2];
        sx += x; sy += y; sz += z;
        zmin = fminf(zmin, z); zmax = fmaxf(zmax, z);
        float u, w;
        {
#pragma clang fp contract(off)
            const float zd = z + EPS_;
            const float x_ = x / zd;
            const float y_ = (-y) / zd;
            u = fx * x_ + cx;
            w = 1.0f - (fy * y_ + cy);
            u = 2.0f * (u - 0.5f);
            w = 2.0f * (w - 0.5f);
        }
        umin = fminf(umin, u); umax = fmaxf(umax, u);
        wmin = fminf(wmin, w); wmax = fmaxf(wmax, w);
    }

    __shared__ float red[4][9];
    float r[9];
    r[0] = wredmin(umin); r[1] = wredmax(umax);
    r[2] = wredmin(wmin); r[3] = wredmax(wmax);
    r[4] = wredmin(zmin); r[5] = wredmax(zmax);
    r[6] = wredsum(sx);   r[7] = wredsum(sy); r[8] = wredsum(sz);
    const int lane = threadIdx.x & 63, wv = threadIdx.x >> 6;
    if (lane == 0) {
#pragma unroll
        for (int q = 0; q < 9; ++q) red[wv][q] = r[q];
    }
    __syncthreads();
    if (threadIdx.x == 0) {
        float* o = out + ((size_t)b * P_ + p) * 9;
        o[0] = fminf(fminf(red[0][0], red[1][0]), fminf(red[2][0], red[3][0]));
        o[1] = fmaxf(fmaxf(red[0][1], red[1][1]), fmaxf(red[2][1], red[3][1]));
        o[2] = fminf(fminf(red[0][2], red[1][2]), fminf(red[2][2], red[3][2]));
        o[3] = fmaxf(fmaxf(red[0][3], red[1][3]), fmaxf(red[2][3], red[3][3]));
        o[4] = fminf(fminf(red[0][4], red[1][4]), fminf(red[2][4], red[3][4]));
        o[5] = fmaxf(fmaxf(red[0][5], red[1][5]), fmaxf(red[2][5], red[3][5]));
        o[6] = red[0][6] + red[1][6] + red[2][6] + red[3][6];
        o[7] = red[0][7] + red[1][7] + red[2][7] + red[3][7];
        o[8] = red[0][8] + red[1][8] + red[2][8] + red[3][8];
    }
}

// ---------------------------------------------------------------------------
// Kernel D: per-batch pair masking + partial sums. One block (64 thr) per batch.
// partial[b*2] = sum(pair_mse*mask), partial[b*2+1] = count.
// ---------------------------------------------------------------------------
__global__ __launch_bounds__(64) void pair_kernel(
        const float* __restrict__ statsS, const float* __restrict__ statsO,
        float* __restrict__ partial) {
#pragma clang fp contract(off)
    const int b = blockIdx.x;
    __shared__ float sS[P_][9];
    __shared__ float sO[P_][9];
    const int t = threadIdx.x;
    for (int i = t; i < 2 * P_ * 9; i += 64) {
        if (i < P_ * 9) sS[i / 9][i % 9] = statsS[(size_t)b * P_ * 9 + i];
        else {
            const int u = i - P_ * 9;
            sO[u / 9][u % 9] = statsO[(size_t)b * P_ * 9 + u];
        }
    }
    __syncthreads();

    const int ps = t >> 3;
    const int po = t & 7;

    // overlap[b, po]: bbox of smpl part po vs bbox of object part po
    const float* ssp = sS[po];
    const float* sop = sO[po];
    const float pcu = (ssp[0] + ssp[1]) * 0.5f;
    const float phu = (ssp[1] - ssp[0]) * 0.5f * 1.5f;
    const float pcw = (ssp[2] + ssp[3]) * 0.5f;
    const float phw = (ssp[3] - ssp[2]) * 0.5f * 1.5f;
    const float px0 = pcu - phu, px1 = pcu + phu;
    const float py0 = pcw - phw, py1 = pcw + phw;
    const float ocu = (sop[0] + sop[1]) * 0.5f;
    const float ohu = (sop[1] - sop[0]) * 0.5f * 1.5f;
    const float ocw = (sop[2] + sop[3]) * 0.5f;
    const float ohw = (sop[3] - sop[2]) * 0.5f * 1.5f;
    const float ox0 = ocu - ohu, ox1 = ocu + ohu;
    const float oy0 = ocw - ohw, oy1 = ocw + ohw;
    const bool ov = !((ox0 > px1) || (px0 > ox1) || (oy0 > py1) || (py0 > oy1));

    // z window: smpl part ps vs object part po
    const float a  = sS[ps][4];
    const float bm = sS[ps][5];
    const float c  = sO[po][4];
    const float d  = sO[po][5];
    const float gap = fminf(fabsf(c - bm), fabsf(a - d));
    const float zd = ((d >= a) && (bm >= c)) ? 0.f : gap;
    const bool m = ov && (zd < ZTH_);

    // pair mse of part means (K is a power of two -> division exact)
    const float ms0 = sS[ps][6] / (float)KS_;
    const float ms1 = sS[ps][7] / (float)KS_;
    const float ms2 = sS[ps][8] / (float)KS_;
    const float mo0 = sO[po][6] / (float)KO_;
    const float mo1 = sO[po][7] / (float)KO_;
    const float mo2 = sO[po][8] / (float)KO_;
    const float d0 = ms0 - mo0, d1 = ms1 - mo1, d2 = ms2 - mo2;
    const float pm = (d0 * d0 + d1 * d1 + d2 * d2) / 3.0f;

    float psum = m ? pm : 0.f;
    float pcnt = m ? 1.f : 0.f;
    psum = wredsum(psum);
    pcnt = wredsum(pcnt);
    if (t == 0) {
        partial[(size_t)b * 2 + 0] = psum;
        partial[(size_t)b * 2 + 1] = pcnt;
    }
}

// ---------------------------------------------------------------------------
// Kernel E: final reduction + output write.
// ---------------------------------------------------------------------------
__global__ __launch_bounds__(256) void final_kernel(
        const float* __restrict__ partial, const float* __restrict__ li,
        float* __restrict__ out) {
    const int t = threadIdx.x;
    float s = partial[(size_t)t * 2 + 0];
    float c = partial[(size_t)t * 2 + 1];
    __shared__ float rs[4], rc[4];
    float ss = wredsum(s), cc = wredsum(c);
    if ((t & 63) == 0) { rs[t >> 6] = ss; rc[t >> 6] = cc; }
    __syncthreads();
    if (t == 0) {
        const float S = rs[0] + rs[1] + rs[2] + rs[3];
        const float C = rc[0] + rc[1] + rc[2] + rc[3];
        out[0] = li[0];
        out[1] = (C > 0.f) ? (S / C) : 0.f;
    }
}

// ---------------------------------------------------------------------------
extern "C" void kernel_launch(void* const* d_in, const int* in_sizes, int n_in,
                              void* d_out, int out_size, void* d_ws, size_t ws_size,
                              hipStream_t stream) {
    const float* smpl = (const float*)d_in[0];
    const float* obj  = (const float*)d_in[1];
    const float* Ks   = (const float*)d_in[2];
    const int*   sidx = (const int*)d_in[3];
    const int*   oidx = (const int*)d_in[4];
    float* out = (float*)d_out;

    float* w = (float*)d_ws;
    float* sumS    = w;                                // B*NBLK_S*3 = 3072
    float* sumO    = sumS + (size_t)B_ * NBLK_S * 3;   // B*NBLK_O*3 = 12288
    float* liw     = sumO + (size_t)B_ * NBLK_O * 3;   // 8 (padded)
    float* statsS  = liw + 8;                          // B*P*9 = 18432
    float* statsO  = statsS + (size_t)B_ * P_ * 9;     // B*P*9 = 18432
    float* partial = statsO + (size_t)B_ * P_ * 9;     // B*2 = 512

    // Order: object stream first (fills L3 with the 201 MB tensor), then the
    // object gather (served from L3), then the smpl pair, then tiny kernels.
    batch_sum_kernel<NO_, NBLK_O><<<B_ * NBLK_O, 256, 0, stream>>>(obj, sumO);
    part_stats_kernel<NO_, KO_><<<B_ * P_, 256, 0, stream>>>(obj, oidx, Ks, statsO);
    batch_sum_kernel<NS_, NBLK_S><<<B_ * NBLK_S, 256, 0, stream>>>(smpl, sumS);
    part_stats_kernel<NS_, KS_><<<B_ * P_, 256, 0, stream>>>(smpl, sidx, Ks, statsS);
    means_li_kernel<<<1, 256, 0, stream>>>(sumS, sumO, liw);
    pair_kernel<<<B_, 64, 0, stream>>>(statsS, statsO, partial);
    final_kernel<<<1, 256, 0, stream>>>(partial, liw, out);
}